// Round 12
// baseline (470.971 us; speedup 1.0000x reference)
//
#include <hip/hip_runtime.h>
#include <hip/hip_bf16.h>
#include <stdint.h>

#define M_DIM 4096
#define K_DIM 4096
#define N_DIM 11008
#define BKT 32                 // K per pipeline step
#define NT (K_DIM / BKT)       // 128 steps
#define GRID_MN 688            // (4096/256) * (11008/256) = 16*43
#define NBLK_M 16

typedef __attribute__((ext_vector_type(8))) short short8;
typedef __attribute__((ext_vector_type(4))) float floatx4;

#define MFMA16 __builtin_amdgcn_mfma_f32_16x16x32_bf16

// f32 -> bf16 round-to-nearest-even
__device__ __forceinline__ short f2bf(float f) {
  union { float f; uint32_t u; } c; c.f = f;
  uint32_t u = c.u;
  u += 0x7FFFu + ((u >> 16) & 1u);
  return (short)(u >> 16);
}

__device__ __forceinline__ void gload_lds16(const void* g, void* l) {
  __builtin_amdgcn_global_load_lds(
      (const __attribute__((address_space(1))) unsigned int*)g,
      (__attribute__((address_space(3))) unsigned int*)l, 16, 0, 0);
}

// ---------------- x: f32 -> bf16, plus exact f32 row sums ----------------
__global__ __launch_bounds__(256) void convert_x_kernel(const float* __restrict__ x,
                                                        short* __restrict__ xb,
                                                        float* __restrict__ rowsum) {
  const int m = blockIdx.x;
  const int t = threadIdx.x;
  const float* row = x + (size_t)m * K_DIM + t * 16;
  short* orow = xb + (size_t)m * K_DIM + t * 16;
  float4 v0 = *(const float4*)(row + 0);
  float4 v1 = *(const float4*)(row + 4);
  float4 v2 = *(const float4*)(row + 8);
  float4 v3 = *(const float4*)(row + 12);
  float sum = v0.x + v0.y + v0.z + v0.w
            + v1.x + v1.y + v1.z + v1.w
            + v2.x + v2.y + v2.z + v2.w
            + v3.x + v3.y + v3.z + v3.w;
  short8 o0, o1;
  o0[0] = f2bf(v0.x); o0[1] = f2bf(v0.y); o0[2] = f2bf(v0.z); o0[3] = f2bf(v0.w);
  o0[4] = f2bf(v1.x); o0[5] = f2bf(v1.y); o0[6] = f2bf(v1.z); o0[7] = f2bf(v1.w);
  o1[0] = f2bf(v2.x); o1[1] = f2bf(v2.y); o1[2] = f2bf(v2.z); o1[3] = f2bf(v2.w);
  o1[4] = f2bf(v3.x); o1[5] = f2bf(v3.y); o1[6] = f2bf(v3.z); o1[7] = f2bf(v3.w);
  *(short8*)(orow) = o0;
  *(short8*)(orow + 8) = o1;
  #pragma unroll
  for (int off = 32; off > 0; off >>= 1) sum += __shfl_down(sum, off);
  __shared__ float part[4];
  if ((t & 63) == 0) part[t >> 6] = sum;
  __syncthreads();
  if (t == 0) rowsum[m] = part[0] + part[1] + part[2] + part[3];
}

// ---------------- w: int32 [K][N] -> bf16 transposed [N][K] ----------------
__global__ __launch_bounds__(256) void convert_w_kernel(const int* __restrict__ w,
                                                        short* __restrict__ wt) {
  __shared__ short tile[64][72];
  const int bk = blockIdx.x * 64;
  const int bn = blockIdx.y * 64;
  const int t = threadIdx.x;
  const int kr = t >> 2;
  const int c0 = (t & 3) * 16;
  const int* src = w + (size_t)(bk + kr) * N_DIM + bn + c0;
  int4 a = *(const int4*)(src + 0);
  int4 b = *(const int4*)(src + 4);
  int4 c = *(const int4*)(src + 8);
  int4 d = *(const int4*)(src + 12);
  short* dst = &tile[kr][c0];
  dst[0]  = f2bf((float)a.x); dst[1]  = f2bf((float)a.y);
  dst[2]  = f2bf((float)a.z); dst[3]  = f2bf((float)a.w);
  dst[4]  = f2bf((float)b.x); dst[5]  = f2bf((float)b.y);
  dst[6]  = f2bf((float)b.z); dst[7]  = f2bf((float)b.w);
  dst[8]  = f2bf((float)c.x); dst[9]  = f2bf((float)c.y);
  dst[10] = f2bf((float)c.z); dst[11] = f2bf((float)c.w);
  dst[12] = f2bf((float)d.x); dst[13] = f2bf((float)d.y);
  dst[14] = f2bf((float)d.z); dst[15] = f2bf((float)d.w);
  __syncthreads();
  const int nr = t >> 2;
  short8 o0, o1;
  #pragma unroll
  for (int j = 0; j < 8; ++j) o0[j] = tile[c0 + j][nr];
  #pragma unroll
  for (int j = 0; j < 8; ++j) o1[j] = tile[c0 + 8 + j][nr];
  short* odst = wt + (size_t)(bn + nr) * K_DIM + bk + c0;
  *(short8*)(odst) = o0;
  *(short8*)(odst + 8) = o1;
}

// ---------------- main GEMM: 256x256 tile, 8 waves, triple-buffer 1-barrier pipeline ----------------
// LDS: lds[3][0=A,1=B][256 rows x 32 k] = 96KB. Swizzle: 64B row = 4 granules;
// store granule = g ^ ((row>>1)&3); read goff = (lg ^ ((lr>>1)&3))*16B.
// Step u (buf C=u%3): {stage tile u+2 -> buf (u+2)%3 [4 gloads]; 12 ds_reads
// of tile u; 32 MFMA (compiler interleaves, fine lgkm); vmcnt(4); s_barrier}.
// RAW: vmcnt(4) pre-barrier retires stages(u+1) in EVERY wave -> barrier exit
// implies tile u+1 resident chip-wide. WAR: all step-u reads are consumed by
// in-step MFMAs (in-order lgkm retirement) before the wave reaches the step-u
// barrier; stage(u+2) into that buffer only issues after it.
__global__ __launch_bounds__(512, 2) void gemm_kernel(const short* __restrict__ xb,
                                                      const short* __restrict__ wt,
                                                      const float* __restrict__ scale,
                                                      const float* __restrict__ offset,
                                                      const float* __restrict__ rowsum,
                                                      float* __restrict__ out) {
  __shared__ short lds[3][2][8192];
  const int tid = threadIdx.x;
  // bijective XCD swizzle: 688 = 8 * 86; n-major so each XCD owns an N-slice
  const int bid = blockIdx.x;
  const int wg = (bid & 7) * (GRID_MN / 8) + (bid >> 3);
  const int bm = (wg % NBLK_M) * 256;
  const int bn = (wg / NBLK_M) * 256;

  const int wid = tid >> 6;
  const int lane = tid & 63;
  const int wr = wid >> 2;              // 0..1 : M half
  const int wc = wid & 3;               // 0..3 : N quarter
  const int lr = lane & 15;
  const int lg = lane >> 4;
  const int goff = (lg ^ ((lr >> 1) & 3)) * 8;  // granule offset (shorts)
  const int arow = wr * 128 + lr;       // + mf*16
  const int brow = wc * 64 + lr;        // + nf*16

  // staging: thread covers 16B slots tid (row srow) and tid+512 (row srow+128)
  const int srow = tid >> 2;
  const int glog = (tid & 3) ^ ((srow >> 1) & 3);
  const size_t toff = (size_t)srow * K_DIM + glog * 8;
  const short* pA = xb + (size_t)bm * K_DIM + toff;
  const short* pB = wt + (size_t)bn * K_DIM + toff;

  auto stg = [&](const short* p, short* region) {
    gload_lds16(p, (char*)region + tid * 16);
    gload_lds16(p + (size_t)128 * K_DIM, (char*)region + (tid + 512) * 16);
  };

  floatx4 acc[8][4];
  const floatx4 zero = {0.f, 0.f, 0.f, 0.f};
  #pragma unroll
  for (int i = 0; i < 8; ++i)
    #pragma unroll
    for (int j = 0; j < 4; ++j) acc[i][j] = zero;

  // ---- prologue: tiles 0,1 -> bufs 0,1 (8 gloads); retire tile 0 ----
  stg(pA, &lds[0][0][0]);
  stg(pB, &lds[0][1][0]);
  stg(pA + BKT, &lds[1][0][0]);
  stg(pB + BKT, &lds[1][1][0]);
  pA += 2 * BKT;
  pB += 2 * BKT;
  asm volatile("s_waitcnt vmcnt(4)" ::: "memory");
  __builtin_amdgcn_s_barrier();

#define STEP(C, CS, DOSTAGE, LASTF)                                            \
  {                                                                            \
    if (DOSTAGE) {                                                             \
      stg(pA, &lds[CS][0][0]);                                                 \
      stg(pB, &lds[CS][1][0]);                                                 \
      pA += BKT; pB += BKT;                                                    \
    }                                                                          \
    const short* As = &lds[C][0][0];                                           \
    const short* Bs = &lds[C][1][0];                                           \
    short8 bv[4], av[8];                                                       \
    _Pragma("unroll")                                                          \
    for (int nf = 0; nf < 4; ++nf)                                             \
      bv[nf] = *(const short8*)(Bs + (brow + nf * 16) * 32 + goff);            \
    _Pragma("unroll")                                                          \
    for (int mf = 0; mf < 8; ++mf)                                             \
      av[mf] = *(const short8*)(As + (arow + mf * 16) * 32 + goff);            \
    _Pragma("unroll")                                                          \
    for (int mf = 0; mf < 8; ++mf)                                             \
      _Pragma("unroll")                                                        \
      for (int nf = 0; nf < 4; ++nf)                                           \
        acc[mf][nf] = MFMA16(av[mf], bv[nf], acc[mf][nf], 0, 0, 0);            \
    if (!(LASTF)) {                                                            \
      if (DOSTAGE) { asm volatile("s_waitcnt vmcnt(4)" ::: "memory"); }        \
      else         { asm volatile("s_waitcnt vmcnt(0)" ::: "memory"); }        \
      __builtin_amdgcn_s_barrier();                                            \
    }                                                                          \
  }

  // steps 0..125 (42 x 3, staging on), then 126 (no stage, drain), 127 (last)
  for (int it = 0; it < (NT - 2) / 3; ++it) {
    STEP(0, 2, 1, 0)
    STEP(1, 0, 1, 0)
    STEP(2, 1, 1, 0)
  }
  STEP(0, 2, 0, 0)
  STEP(1, 0, 0, 1)
#undef STEP

  // ---- epilogue: out = (G + offset[n]*rowsum[m]) * scale[n] ----
  const int orow0 = bm + wr * 128 + lg * 4;
  const int ocol0 = bn + wc * 64 + lr;
  float4 rsv[8];
  #pragma unroll
  for (int amf = 0; amf < 8; ++amf)
    rsv[amf] = *(const float4*)&rowsum[orow0 + amf * 16];
  #pragma unroll
  for (int anf = 0; anf < 4; ++anf) {
    const int n = ocol0 + anf * 16;
    const float sc = scale[n];
    const float of = offset[n];
    #pragma unroll
    for (int amf = 0; amf < 8; ++amf) {
      const int mbase = orow0 + amf * 16;
      const float4 rv = rsv[amf];
      out[(size_t)(mbase + 0) * N_DIM + n] = (acc[amf][anf][0] + of * rv.x) * sc;
      out[(size_t)(mbase + 1) * N_DIM + n] = (acc[amf][anf][1] + of * rv.y) * sc;
      out[(size_t)(mbase + 2) * N_DIM + n] = (acc[amf][anf][2] + of * rv.z) * sc;
      out[(size_t)(mbase + 3) * N_DIM + n] = (acc[amf][anf][3] + of * rv.w) * sc;
    }
  }
}

// ---------------- fallback (ws too small): exact f32 tiled GEMM ----------------
__global__ __launch_bounds__(256) void fallback_gemm(const float* __restrict__ x,
                                                     const int* __restrict__ w,
                                                     const float* __restrict__ scale,
                                                     const float* __restrict__ offset,
                                                     float* __restrict__ out) {
  __shared__ float xs[32][33];
  __shared__ float bs[32][33];
  const int bm = blockIdx.y * 32, bn = blockIdx.x * 32;
  const int t = threadIdx.x;
  const int tm = t >> 5, tn = t & 31;
  float acc[4] = {0.f, 0.f, 0.f, 0.f};
  for (int k0 = 0; k0 < K_DIM; k0 += 32) {
    #pragma unroll
    for (int i = 0; i < 4; ++i) {
      int idx = t + i * 256; int r = idx >> 5, c = idx & 31;
      xs[r][c] = x[(size_t)(bm + r) * K_DIM + k0 + c];
      bs[r][c] = ((float)w[(size_t)(k0 + r) * N_DIM + bn + c] + offset[bn + c]) * scale[bn + c];
    }
    __syncthreads();
    #pragma unroll 8
    for (int kk = 0; kk < 32; ++kk) {
      float wv = bs[kk][tn];
      #pragma unroll
      for (int i = 0; i < 4; ++i) acc[i] += xs[tm + 8 * i][kk] * wv;
    }
    __syncthreads();
  }
  #pragma unroll
  for (int i = 0; i < 4; ++i)
    out[(size_t)(bm + tm + 8 * i) * N_DIM + bn + tn] = acc[i];
}

extern "C" void kernel_launch(void* const* d_in, const int* in_sizes, int n_in,
                              void* d_out, int out_size, void* d_ws, size_t ws_size,
                              hipStream_t stream) {
  const float* x      = (const float*)d_in[0];
  const int*   w      = (const int*)d_in[1];
  const float* scale  = (const float*)d_in[2];
  const float* offset = (const float*)d_in[3];
  float* out = (float*)d_out;

  const size_t xb_bytes = (size_t)M_DIM * K_DIM * 2;
  const size_t wt_bytes = (size_t)N_DIM * K_DIM * 2;
  const size_t rs_bytes = (size_t)M_DIM * 4;

  if (ws_size >= xb_bytes + wt_bytes + rs_bytes) {
    short* xb = (short*)d_ws;
    short* wt = (short*)((char*)d_ws + xb_bytes);
    float* rowsum = (float*)((char*)d_ws + xb_bytes + wt_bytes);
    convert_x_kernel<<<M_DIM, 256, 0, stream>>>(x, xb, rowsum);
    convert_w_kernel<<<dim3(K_DIM / 64, N_DIM / 64), 256, 0, stream>>>(w, wt);
    gemm_kernel<<<GRID_MN, 512, 0, stream>>>(xb, wt, scale, offset, rowsum, out);
  } else {
    fallback_gemm<<<dim3(N_DIM / 32, M_DIM / 32), 256, 0, stream>>>(x, w, scale, offset, out);
  }
}

// Round 13
// 428.747 us; speedup vs baseline: 1.0985x; 1.0985x over previous
//
#include <hip/hip_runtime.h>
#include <hip/hip_bf16.h>
#include <stdint.h>

#define M_DIM 4096
#define K_DIM 4096
#define N_DIM 11008
#define BKT 64                 // K per tile
#define NT (K_DIM / BKT)       // 64 k-tiles, 32 iterations of 2
#define GRID_MN 688            // (4096/256) * (11008/256) = 16*43
#define NBLK_M 16

typedef __attribute__((ext_vector_type(8))) short short8;
typedef __attribute__((ext_vector_type(4))) float floatx4;

#define MFMA16 __builtin_amdgcn_mfma_f32_16x16x32_bf16
#define BAR() __builtin_amdgcn_s_barrier()
#define LGKM0() do { asm volatile("s_waitcnt lgkmcnt(0)" ::: "memory"); __builtin_amdgcn_sched_barrier(0); } while (0)
#define LGKM8() asm volatile("s_waitcnt lgkmcnt(8)" ::: "memory")
#define VM4() asm volatile("s_waitcnt vmcnt(4)" ::: "memory")
#define VM0() asm volatile("s_waitcnt vmcnt(0)" ::: "memory")

// f32 -> bf16 round-to-nearest-even
__device__ __forceinline__ short f2bf(float f) {
  union { float f; uint32_t u; } c; c.f = f;
  uint32_t u = c.u;
  u += 0x7FFFu + ((u >> 16) & 1u);
  return (short)(u >> 16);
}

__device__ __forceinline__ void gload_lds16(const void* g, void* l) {
  __builtin_amdgcn_global_load_lds(
      (const __attribute__((address_space(1))) unsigned int*)g,
      (__attribute__((address_space(3))) unsigned int*)l, 16, 0, 0);
}

// ---------------- x: f32 -> bf16, plus exact f32 row sums ----------------
__global__ __launch_bounds__(256) void convert_x_kernel(const float* __restrict__ x,
                                                        short* __restrict__ xb,
                                                        float* __restrict__ rowsum) {
  const int m = blockIdx.x;
  const int t = threadIdx.x;
  const float* row = x + (size_t)m * K_DIM + t * 16;
  short* orow = xb + (size_t)m * K_DIM + t * 16;
  float4 v0 = *(const float4*)(row + 0);
  float4 v1 = *(const float4*)(row + 4);
  float4 v2 = *(const float4*)(row + 8);
  float4 v3 = *(const float4*)(row + 12);
  float sum = v0.x + v0.y + v0.z + v0.w
            + v1.x + v1.y + v1.z + v1.w
            + v2.x + v2.y + v2.z + v2.w
            + v3.x + v3.y + v3.z + v3.w;
  short8 o0, o1;
  o0[0] = f2bf(v0.x); o0[1] = f2bf(v0.y); o0[2] = f2bf(v0.z); o0[3] = f2bf(v0.w);
  o0[4] = f2bf(v1.x); o0[5] = f2bf(v1.y); o0[6] = f2bf(v1.z); o0[7] = f2bf(v1.w);
  o1[0] = f2bf(v2.x); o1[1] = f2bf(v2.y); o1[2] = f2bf(v2.z); o1[3] = f2bf(v2.w);
  o1[4] = f2bf(v3.x); o1[5] = f2bf(v3.y); o1[6] = f2bf(v3.z); o1[7] = f2bf(v3.w);
  *(short8*)(orow) = o0;
  *(short8*)(orow + 8) = o1;
  #pragma unroll
  for (int off = 32; off > 0; off >>= 1) sum += __shfl_down(sum, off);
  __shared__ float part[4];
  if ((t & 63) == 0) part[t >> 6] = sum;
  __syncthreads();
  if (t == 0) rowsum[m] = part[0] + part[1] + part[2] + part[3];
}

// ---------------- w: int32 [K][N] -> bf16 transposed [N][K] ----------------
__global__ __launch_bounds__(256) void convert_w_kernel(const int* __restrict__ w,
                                                        short* __restrict__ wt) {
  __shared__ short tile[64][72];
  const int bk = blockIdx.x * 64;
  const int bn = blockIdx.y * 64;
  const int t = threadIdx.x;
  const int kr = t >> 2;
  const int c0 = (t & 3) * 16;
  const int* src = w + (size_t)(bk + kr) * N_DIM + bn + c0;
  int4 a = *(const int4*)(src + 0);
  int4 b = *(const int4*)(src + 4);
  int4 c = *(const int4*)(src + 8);
  int4 d = *(const int4*)(src + 12);
  short* dst = &tile[kr][c0];
  dst[0]  = f2bf((float)a.x); dst[1]  = f2bf((float)a.y);
  dst[2]  = f2bf((float)a.z); dst[3]  = f2bf((float)a.w);
  dst[4]  = f2bf((float)b.x); dst[5]  = f2bf((float)b.y);
  dst[6]  = f2bf((float)b.z); dst[7]  = f2bf((float)b.w);
  dst[8]  = f2bf((float)c.x); dst[9]  = f2bf((float)c.y);
  dst[10] = f2bf((float)c.z); dst[11] = f2bf((float)c.w);
  dst[12] = f2bf((float)d.x); dst[13] = f2bf((float)d.y);
  dst[14] = f2bf((float)d.z); dst[15] = f2bf((float)d.w);
  __syncthreads();
  const int nr = t >> 2;
  short8 o0, o1;
  #pragma unroll
  for (int j = 0; j < 8; ++j) o0[j] = tile[c0 + j][nr];
  #pragma unroll
  for (int j = 0; j < 8; ++j) o1[j] = tile[c0 + 8 + j][nr];
  short* odst = wt + (size_t)(bn + nr) * K_DIM + bk + c0;
  *(short8*)(odst) = o0;
  *(short8*)(odst + 8) = o1;
}

// ---------------- main GEMM: 256x256, 8 waves, m201-style 8-phase / 2-K-tile iteration ----------------
// LDS: lds[tile-parity buf][region: 0=A-half0,1=A-half1,2=B-half0,3=B-half1][16KB].
// Swizzle: 16B granule g of row stored at g ^ (row & 7).
// Iter i: t0=2i (buf0), t1=2i+1 (buf1). Phases (reads 12/8/4/0 per tile,
// ONE half-tile stage per phase, placed AFTER its region's last reader):
//  P1: rd a03,b0(t0); stg A1(t1)->[1][1];  lgkm8; BAR; lgkm0; Q00(t0); BAR
//  P2: rd a47(t0);    stg B1(t1)->[1][3];         BAR; lgkm0; Q10(t0); BAR
//  P3: rd b1(t0);     stg A0(t0+2)->[0][0];       BAR; lgkm0; Q01(t0); BAR
//  P4:                stg B0(t0+2)->[0][2]; VM4;  BAR;        Q11(t0); BAR
//  P5-P8: mirror on t1 (stages A1(t0+2),B1(t0+2),A0(t1+2),B0(t1+2); VM4 at P8)
// FIFO ledger: vmcnt(4)@P4(i) retires {A0,B0(P7,P8 of i-1), A1,B1(P1,P2 of i)}
// = ALL of t1(i) before P5 reads; vmcnt(4)@P8(i) retires {A0,A1,B0,B1}(t0+2)
// = all of t0(i+1) before P1(i+1). WAR: each stage >=1 barrier after chip-wide
// lgkm-retirement of its region's last readers. Prologue (6 halves + vmcnt(4))
// establishes the invariant exactly; final iter peeled with vmcnt(0)@P4.
__global__ __launch_bounds__(512, 2) void gemm_kernel(const short* __restrict__ xb,
                                                      const short* __restrict__ wt,
                                                      const float* __restrict__ scale,
                                                      const float* __restrict__ offset,
                                                      const float* __restrict__ rowsum,
                                                      float* __restrict__ out) {
  __shared__ short lds[2][4][8192];
  const int tid = threadIdx.x;
  // bijective XCD swizzle: 688 = 8 * 86; n-major so each XCD owns an N-slice
  const int bid = blockIdx.x;
  const int wg = (bid & 7) * (GRID_MN / 8) + (bid >> 3);
  const int bm = (wg % NBLK_M) * 256;
  const int bn = (wg / NBLK_M) * 256;

  const int wid = tid >> 6;
  const int lane = tid & 63;
  const int wr = wid >> 2;              // 0..1 : M half -> A region
  const int wc = wid & 3;               // 0..3 : N quarter
  const int hb = wc >> 1;               // B half-region
  const int lr = lane & 15;
  const int lg = lane >> 4;
  const int swz = lr & 7;
  const int gk0 = (lg ^ swz) * 8;
  const int gk1 = ((lg ^ 4) ^ swz) * 8;
  const int brow = (wc & 1) * 64 + lr;

  // staging: thread covers 16B slots tid and tid+512 of a 16KB half-tile
  const int srow = tid >> 3;
  const int glog = (tid & 7) ^ (srow & 7);
  const size_t toff = (size_t)srow * K_DIM + glog * 8;
  const short* pAh0 = xb + (size_t)bm * K_DIM + toff;
  const short* pAh1 = xb + ((size_t)bm + 128) * K_DIM + toff;
  const short* pBh0 = wt + (size_t)bn * K_DIM + toff;
  const short* pBh1 = wt + ((size_t)bn + 128) * K_DIM + toff;

  auto stage2 = [&](const short* p, short* region) {
    gload_lds16(p, (char*)region + tid * 16);
    gload_lds16(p + (size_t)64 * K_DIM, (char*)region + (tid + 512) * 16);
  };

  floatx4 acc[8][4];
  const floatx4 zero = {0.f, 0.f, 0.f, 0.f};
  #pragma unroll
  for (int i = 0; i < 8; ++i)
    #pragma unroll
    for (int j = 0; j < 4; ++j) acc[i][j] = zero;

  short8 a03[4][2], a47[4][2], b0[2][2], b1[2][2];
  const short* const As[2] = {&lds[0][wr][0], &lds[1][wr][0]};
  const short* const Bs[2] = {&lds[0][2 + hb][0], &lds[1][2 + hb][0]};

  auto rdA03 = [&](const short* A) {
    #pragma unroll
    for (int mf = 0; mf < 4; ++mf) {
      const short* p = A + (mf * 16 + lr) * 64;
      a03[mf][0] = *(const short8*)(p + gk0);
      a03[mf][1] = *(const short8*)(p + gk1);
    }
  };
  auto rdA47 = [&](const short* A) {
    #pragma unroll
    for (int mf = 0; mf < 4; ++mf) {
      const short* p = A + ((mf + 4) * 16 + lr) * 64;
      a47[mf][0] = *(const short8*)(p + gk0);
      a47[mf][1] = *(const short8*)(p + gk1);
    }
  };
  auto rdB0 = [&](const short* B) {
    #pragma unroll
    for (int nf = 0; nf < 2; ++nf) {
      const short* p = B + (brow + nf * 16) * 64;
      b0[nf][0] = *(const short8*)(p + gk0);
      b0[nf][1] = *(const short8*)(p + gk1);
    }
  };
  auto rdB1 = [&](const short* B) {
    #pragma unroll
    for (int nf = 0; nf < 2; ++nf) {
      const short* p = B + (brow + (nf + 2) * 16) * 64;
      b1[nf][0] = *(const short8*)(p + gk0);
      b1[nf][1] = *(const short8*)(p + gk1);
    }
  };
  auto q00 = [&]() {
    __builtin_amdgcn_s_setprio(1);
    #pragma unroll
    for (int mf = 0; mf < 4; ++mf)
      #pragma unroll
      for (int nf = 0; nf < 2; ++nf) {
        acc[mf][nf] = MFMA16(a03[mf][0], b0[nf][0], acc[mf][nf], 0, 0, 0);
        acc[mf][nf] = MFMA16(a03[mf][1], b0[nf][1], acc[mf][nf], 0, 0, 0);
      }
    __builtin_amdgcn_s_setprio(0);
  };
  auto q10 = [&]() {
    __builtin_amdgcn_s_setprio(1);
    #pragma unroll
    for (int mf = 0; mf < 4; ++mf)
      #pragma unroll
      for (int nf = 0; nf < 2; ++nf) {
        acc[mf + 4][nf] = MFMA16(a47[mf][0], b0[nf][0], acc[mf + 4][nf], 0, 0, 0);
        acc[mf + 4][nf] = MFMA16(a47[mf][1], b0[nf][1], acc[mf + 4][nf], 0, 0, 0);
      }
    __builtin_amdgcn_s_setprio(0);
  };
  auto q01 = [&]() {
    __builtin_amdgcn_s_setprio(1);
    #pragma unroll
    for (int mf = 0; mf < 4; ++mf)
      #pragma unroll
      for (int nf = 0; nf < 2; ++nf) {
        acc[mf][nf + 2] = MFMA16(a03[mf][0], b1[nf][0], acc[mf][nf + 2], 0, 0, 0);
        acc[mf][nf + 2] = MFMA16(a03[mf][1], b1[nf][1], acc[mf][nf + 2], 0, 0, 0);
      }
    __builtin_amdgcn_s_setprio(0);
  };
  auto q11 = [&]() {
    __builtin_amdgcn_s_setprio(1);
    #pragma unroll
    for (int mf = 0; mf < 4; ++mf)
      #pragma unroll
      for (int nf = 0; nf < 2; ++nf) {
        acc[mf + 4][nf + 2] = MFMA16(a47[mf][0], b1[nf][0], acc[mf + 4][nf + 2], 0, 0, 0);
        acc[mf + 4][nf + 2] = MFMA16(a47[mf][1], b1[nf][1], acc[mf + 4][nf + 2], 0, 0, 0);
      }
    __builtin_amdgcn_s_setprio(0);
  };

  // ---- prologue: FIFO = A0(0),B0(0),A1(0),B1(0),A0(1),B0(1); vmcnt(4) ----
  stage2(pAh0, &lds[0][0][0]); pAh0 += BKT;
  stage2(pBh0, &lds[0][2][0]); pBh0 += BKT;
  stage2(pAh1, &lds[0][1][0]); pAh1 += BKT;
  stage2(pBh1, &lds[0][3][0]); pBh1 += BKT;
  stage2(pAh0, &lds[1][0][0]); pAh0 += BKT;
  stage2(pBh0, &lds[1][2][0]); pBh0 += BKT;
  VM4();   // tile0 fully resident; A0(1),B0(1) in flight
  BAR();

  for (int i = 0; i < NT / 2 - 1; ++i) {
    // ---- P1 ----
    rdA03(As[0]); rdB0(Bs[0]);
    stage2(pAh1, &lds[1][1][0]); pAh1 += BKT;     // A1(t1)
    LGKM8();
    BAR(); LGKM0(); q00(); BAR();
    // ---- P2 ----
    rdA47(As[0]);
    stage2(pBh1, &lds[1][3][0]); pBh1 += BKT;     // B1(t1)
    BAR(); LGKM0(); q10(); BAR();
    // ---- P3 ----
    rdB1(Bs[0]);
    stage2(pAh0, &lds[0][0][0]); pAh0 += BKT;     // A0(t0+2)
    BAR(); LGKM0(); q01(); BAR();
    // ---- P4 ----
    stage2(pBh0, &lds[0][2][0]); pBh0 += BKT;     // B0(t0+2)
    VM4();                                        // retire all of t1
    BAR(); q11(); BAR();
    // ---- P5 ----
    rdA03(As[1]); rdB0(Bs[1]);
    stage2(pAh1, &lds[0][1][0]); pAh1 += BKT;     // A1(t0+2)
    LGKM8();
    BAR(); LGKM0(); q00(); BAR();
    // ---- P6 ----
    rdA47(As[1]);
    stage2(pBh1, &lds[0][3][0]); pBh1 += BKT;     // B1(t0+2)
    BAR(); LGKM0(); q10(); BAR();
    // ---- P7 ----
    rdB1(Bs[1]);
    stage2(pAh0, &lds[1][0][0]); pAh0 += BKT;     // A0(t1+2)
    BAR(); LGKM0(); q01(); BAR();
    // ---- P8 ----
    stage2(pBh0, &lds[1][2][0]); pBh0 += BKT;     // B0(t1+2)
    VM4();                                        // retire all of t0+2
    BAR(); q11(); BAR();
  }

  // ---- tail iter (t0=62, t1=63): stage only A1(63),B1(63); drain @P4 ----
  rdA03(As[0]); rdB0(Bs[0]);
  stage2(pAh1, &lds[1][1][0]);                    // A1(63)
  LGKM8();
  BAR(); LGKM0(); q00(); BAR();
  rdA47(As[0]);
  stage2(pBh1, &lds[1][3][0]);                    // B1(63)
  BAR(); LGKM0(); q10(); BAR();
  rdB1(Bs[0]);
  BAR(); LGKM0(); q01(); BAR();
  VM0();                                          // tile 63 fully resident
  BAR(); q11(); BAR();
  rdA03(As[1]); rdB0(Bs[1]);
  LGKM8();
  BAR(); LGKM0(); q00(); BAR();
  rdA47(As[1]);
  BAR(); LGKM0(); q10(); BAR();
  rdB1(Bs[1]);
  BAR(); LGKM0(); q01(); BAR();
  q11();

  // ---- epilogue: out = (G + offset[n]*rowsum[m]) * scale[n] ----
  const int orow0 = bm + wr * 128 + lg * 4;
  const int ocol0 = bn + wc * 64 + lr;
  float4 rsv[8];
  #pragma unroll
  for (int amf = 0; amf < 8; ++amf)
    rsv[amf] = *(const float4*)&rowsum[orow0 + amf * 16];
  #pragma unroll
  for (int anf = 0; anf < 4; ++anf) {
    const int n = ocol0 + anf * 16;
    const float sc = scale[n];
    const float of = offset[n];
    #pragma unroll
    for (int amf = 0; amf < 8; ++amf) {
      const int mbase = orow0 + amf * 16;
      const float4 rv = rsv[amf];
      out[(size_t)(mbase + 0) * N_DIM + n] = (acc[amf][anf][0] + of * rv.x) * sc;
      out[(size_t)(mbase + 1) * N_DIM + n] = (acc[amf][anf][1] + of * rv.y) * sc;
      out[(size_t)(mbase + 2) * N_DIM + n] = (acc[amf][anf][2] + of * rv.z) * sc;
      out[(size_t)(mbase + 3) * N_DIM + n] = (acc[amf][anf][3] + of * rv.w) * sc;
    }
  }
}

// ---------------- fallback (ws too small): exact f32 tiled GEMM ----------------
__global__ __launch_bounds__(256) void fallback_gemm(const float* __restrict__ x,
                                                     const int* __restrict__ w,
                                                     const float* __restrict__ scale,
                                                     const float* __restrict__ offset,
                                                     float* __restrict__ out) {
  __shared__ float xs[32][33];
  __shared__ float bs[32][33];
  const int bm = blockIdx.y * 32, bn = blockIdx.x * 32;
  const int t = threadIdx.x;
  const int tm = t >> 5, tn = t & 31;
  float acc[4] = {0.f, 0.f, 0.f, 0.f};
  for (int k0 = 0; k0 < K_DIM; k0 += 32) {
    #pragma unroll
    for (int i = 0; i < 4; ++i) {
      int idx = t + i * 256; int r = idx >> 5, c = idx & 31;
      xs[r][c] = x[(size_t)(bm + r) * K_DIM + k0 + c];
      bs[r][c] = ((float)w[(size_t)(k0 + r) * N_DIM + bn + c] + offset[bn + c]) * scale[bn + c];
    }
    __syncthreads();
    #pragma unroll 8
    for (int kk = 0; kk < 32; ++kk) {
      float wv = bs[kk][tn];
      #pragma unroll
      for (int i = 0; i < 4; ++i) acc[i] += xs[tm + 8 * i][kk] * wv;
    }
    __syncthreads();
  }
  #pragma unroll
  for (int i = 0; i < 4; ++i)
    out[(size_t)(bm + tm + 8 * i) * N_DIM + bn + tn] = acc[i];
}

extern "C" void kernel_launch(void* const* d_in, const int* in_sizes, int n_in,
                              void* d_out, int out_size, void* d_ws, size_t ws_size,
                              hipStream_t stream) {
  const float* x      = (const float*)d_in[0];
  const int*   w      = (const int*)d_in[1];
  const float* scale  = (const float*)d_in[2];
  const float* offset = (const float*)d_in[3];
  float* out = (float*)d_out;

  const size_t xb_bytes = (size_t)M_DIM * K_DIM * 2;
  const size_t wt_bytes = (size_t)N_DIM * K_DIM * 2;
  const size_t rs_bytes = (size_t)M_DIM * 4;

  if (ws_size >= xb_bytes + wt_bytes + rs_bytes) {
    short* xb = (short*)d_ws;
    short* wt = (short*)((char*)d_ws + xb_bytes);
    float* rowsum = (float*)((char*)d_ws + xb_bytes + wt_bytes);
    convert_x_kernel<<<M_DIM, 256, 0, stream>>>(x, xb, rowsum);
    convert_w_kernel<<<dim3(K_DIM / 64, N_DIM / 64), 256, 0, stream>>>(w, wt);
    gemm_kernel<<<GRID_MN, 512, 0, stream>>>(xb, wt, scale, offset, rowsum, out);
  } else {
    fallback_gemm<<<dim3(N_DIM / 32, M_DIM / 32), 256, 0, stream>>>(x, w, scale, offset, out);
  }
}

// Round 14
// 405.052 us; speedup vs baseline: 1.1627x; 1.0585x over previous
//
#include <hip/hip_runtime.h>
#include <hip/hip_bf16.h>
#include <stdint.h>

#define M_DIM 4096
#define K_DIM 4096
#define N_DIM 11008
#define BKT 64                 // K per tile
#define NT (K_DIM / BKT)       // 64 k-tiles
#define GRID_MN 688            // (4096/256) * (11008/256) = 16*43
#define NBLK_M 16

typedef __attribute__((ext_vector_type(8))) short short8;
typedef __attribute__((ext_vector_type(4))) float floatx4;

// f32 -> bf16 round-to-nearest-even
__device__ __forceinline__ short f2bf(float f) {
  union { float f; uint32_t u; } c; c.f = f;
  uint32_t u = c.u;
  u += 0x7FFFu + ((u >> 16) & 1u);
  return (short)(u >> 16);
}

__device__ __forceinline__ void gload_lds16(const void* g, void* l) {
  __builtin_amdgcn_global_load_lds(
      (const __attribute__((address_space(1))) unsigned int*)g,
      (__attribute__((address_space(3))) unsigned int*)l, 16, 0, 0);
}

// ---------------- x: f32 -> bf16, plus exact f32 row sums ----------------
__global__ __launch_bounds__(256) void convert_x_kernel(const float* __restrict__ x,
                                                        short* __restrict__ xb,
                                                        float* __restrict__ rowsum) {
  const int m = blockIdx.x;
  const int t = threadIdx.x;
  const float* row = x + (size_t)m * K_DIM + t * 16;
  short* orow = xb + (size_t)m * K_DIM + t * 16;
  float4 v0 = *(const float4*)(row + 0);
  float4 v1 = *(const float4*)(row + 4);
  float4 v2 = *(const float4*)(row + 8);
  float4 v3 = *(const float4*)(row + 12);
  float sum = v0.x + v0.y + v0.z + v0.w
            + v1.x + v1.y + v1.z + v1.w
            + v2.x + v2.y + v2.z + v2.w
            + v3.x + v3.y + v3.z + v3.w;
  short8 o0, o1;
  o0[0] = f2bf(v0.x); o0[1] = f2bf(v0.y); o0[2] = f2bf(v0.z); o0[3] = f2bf(v0.w);
  o0[4] = f2bf(v1.x); o0[5] = f2bf(v1.y); o0[6] = f2bf(v1.z); o0[7] = f2bf(v1.w);
  o1[0] = f2bf(v2.x); o1[1] = f2bf(v2.y); o1[2] = f2bf(v2.z); o1[3] = f2bf(v2.w);
  o1[4] = f2bf(v3.x); o1[5] = f2bf(v3.y); o1[6] = f2bf(v3.z); o1[7] = f2bf(v3.w);
  *(short8*)(orow) = o0;
  *(short8*)(orow + 8) = o1;
  #pragma unroll
  for (int off = 32; off > 0; off >>= 1) sum += __shfl_down(sum, off);
  __shared__ float part[4];
  if ((t & 63) == 0) part[t >> 6] = sum;
  __syncthreads();
  if (t == 0) rowsum[m] = part[0] + part[1] + part[2] + part[3];
}

// ---------------- w: int32 [K][N] -> bf16 transposed [N][K] ----------------
__global__ __launch_bounds__(256) void convert_w_kernel(const int* __restrict__ w,
                                                        short* __restrict__ wt) {
  __shared__ short tile[64][72];
  const int bk = blockIdx.x * 64;
  const int bn = blockIdx.y * 64;
  const int t = threadIdx.x;
  const int kr = t >> 2;
  const int c0 = (t & 3) * 16;
  const int* src = w + (size_t)(bk + kr) * N_DIM + bn + c0;
  int4 a = *(const int4*)(src + 0);
  int4 b = *(const int4*)(src + 4);
  int4 c = *(const int4*)(src + 8);
  int4 d = *(const int4*)(src + 12);
  short* dst = &tile[kr][c0];
  dst[0]  = f2bf((float)a.x); dst[1]  = f2bf((float)a.y);
  dst[2]  = f2bf((float)a.z); dst[3]  = f2bf((float)a.w);
  dst[4]  = f2bf((float)b.x); dst[5]  = f2bf((float)b.y);
  dst[6]  = f2bf((float)b.z); dst[7]  = f2bf((float)b.w);
  dst[8]  = f2bf((float)c.x); dst[9]  = f2bf((float)c.y);
  dst[10] = f2bf((float)c.z); dst[11] = f2bf((float)c.w);
  dst[12] = f2bf((float)d.x); dst[13] = f2bf((float)d.y);
  dst[14] = f2bf((float)d.z); dst[15] = f2bf((float)d.w);
  __syncthreads();
  const int nr = t >> 2;
  short8 o0, o1;
  #pragma unroll
  for (int j = 0; j < 8; ++j) o0[j] = tile[c0 + j][nr];
  #pragma unroll
  for (int j = 0; j < 8; ++j) o1[j] = tile[c0 + 8 + j][nr];
  short* odst = wt + (size_t)(bn + nr) * K_DIM + bk + c0;
  *(short8*)(odst) = o0;
  *(short8*)(odst + 8) = o1;
}

// ---------------- main GEMM: 256x256 tile, 8 waves, JIT-refill pipeline (R7, best) ----------------
// LDS: [buf][region: 0=A0,1=A1,2=B0,3=B1][128 rows x 64 k]
// Swizzle: 16B granule g of row stored at g ^ (row & 7).
// Step u (buf g=u&1), 4 barriers/step, reads always 1 phase ahead of use:
//   P1{read a47(u); lgkm(8); BAR; stage A1(u+1)->!g;  Q00=a03*b0}
//   P2{read b1(u);  lgkm(4); BAR; stage A0(u+2)->g;   Q10=a47*b0}
//   P3{             lgkm(0); BAR; stage B0(u+2)->g;   Q01=a03*b1}
//   P4{stage B1(u+2)->g; vmcnt(6); BAR; read a03,b0(u+1) from !g; Q11=a47*b1}
// Safety: every stage issues only after a barrier that follows chip-wide
// retirement of all reads from its region (lgkm(8/4/0) are pre-barrier).
// vmcnt FIFO: 14 outstanding at P4's vmcnt(6) -> retires exactly tile u+1.
__global__ __launch_bounds__(512, 2) void gemm_kernel(const short* __restrict__ xb,
                                                      const short* __restrict__ wt,
                                                      const float* __restrict__ scale,
                                                      const float* __restrict__ offset,
                                                      const float* __restrict__ rowsum,
                                                      float* __restrict__ out) {
  __shared__ short lds[2][4][8192];
  const int tid = threadIdx.x;
  // bijective XCD swizzle: 688 = 8 * 86; n-major so each XCD owns an N-slice
  const int bid = blockIdx.x;
  const int wg = (bid & 7) * (GRID_MN / 8) + (bid >> 3);
  const int bm = (wg % NBLK_M) * 256;
  const int bn = (wg / NBLK_M) * 256;

  const int wid = tid >> 6;
  const int lane = tid & 63;
  const int wr = wid >> 2;              // 0..1 : M half
  const int wc = wid & 3;               // 0..3 : N quarter
  const int hb = wc >> 1;               // which B half-region
  const int lr = lane & 15;
  const int lg = lane >> 4;
  const int swz = lr & 7;               // = row & 7 for every row this lane reads
  const int gk0 = (lg ^ swz) * 8;       // k-half 0 granule (shorts)
  const int gk1 = ((lg ^ 4) ^ swz) * 8; // k-half 1 granule (shorts)
  const int brow = (wc & 1) * 64 + lr;

  // staging: thread covers 16B slots tid and tid+512 of a 16KB half-tile
  const int srow = tid >> 3;                       // rows srow and srow+64
  const int glog = (tid & 7) ^ (srow & 7);         // logical granule for this slot

  auto stage = [&](const short* opbase, int rowbase, int half, int kt, short* region) {
    const short* s0 = opbase + (size_t)(rowbase + half * 128 + srow) * K_DIM + kt * BKT + glog * 8;
    gload_lds16(s0, (char*)region + tid * 16);
    const short* s1 = opbase + (size_t)(rowbase + half * 128 + srow + 64) * K_DIM + kt * BKT + glog * 8;
    gload_lds16(s1, (char*)region + (tid + 512) * 16);
  };

  floatx4 acc[8][4];
  const floatx4 zero = {0.f, 0.f, 0.f, 0.f};
  #pragma unroll
  for (int i = 0; i < 8; ++i)
    #pragma unroll
    for (int j = 0; j < 4; ++j) acc[i][j] = zero;

  // ---- prologue ----
  stage(xb, bm, 0, 0, &lds[0][0][0]);
  stage(xb, bm, 1, 0, &lds[0][1][0]);
  stage(wt, bn, 0, 0, &lds[0][2][0]);
  stage(wt, bn, 1, 0, &lds[0][3][0]);
  asm volatile("s_waitcnt vmcnt(0)" ::: "memory");
  __builtin_amdgcn_s_barrier();

  short8 a03[4][2], a47[4][2], b0[2][2], b1[2][2];
  {
    // read a03(0), b0(0): 12 lgkm outstanding entering the loop
    const short* As = &lds[0][wr][0];
    #pragma unroll
    for (int mf = 0; mf < 4; ++mf) {
      const short* p = As + (mf * 16 + lr) * 64;
      a03[mf][0] = *(const short8*)(p + gk0);
      a03[mf][1] = *(const short8*)(p + gk1);
    }
    const short* Bsp = &lds[0][2 + hb][0];
    #pragma unroll
    for (int nf = 0; nf < 2; ++nf) {
      const short* p = Bsp + (brow + nf * 16) * 64;
      b0[nf][0] = *(const short8*)(p + gk0);
      b0[nf][1] = *(const short8*)(p + gk1);
    }
  }
  // stage tile1 {A0,B0,B1}: 6 vm outstanding entering the loop (A1(1) at P1(0))
  stage(xb, bm, 0, 1, &lds[1][0][0]);
  stage(wt, bn, 0, 1, &lds[1][2][0]);
  stage(wt, bn, 1, 1, &lds[1][3][0]);

  for (int u = 0; u < NT; ++u) {
    const int g = u & 1;
    const short* As = &lds[g][wr][0];
    const short* Bs = &lds[g][2 + hb][0];

    // ========== P1: read a47(u); lgkm(8); BAR; stage A1(u+1); Q00 ==========
    #pragma unroll
    for (int mf = 0; mf < 4; ++mf) {
      const short* p = As + ((mf + 4) * 16 + lr) * 64;
      a47[mf][0] = *(const short8*)(p + gk0);
      a47[mf][1] = *(const short8*)(p + gk1);
    }
    asm volatile("s_waitcnt lgkmcnt(8)" ::: "memory");  // a03,b0(u) retired
    __builtin_amdgcn_s_barrier();
    if (u + 1 < NT) stage(xb, bm, 1, u + 1, &lds[g ^ 1][1][0]);
    __builtin_amdgcn_s_setprio(1);
    #pragma unroll
    for (int mf = 0; mf < 4; ++mf)
      #pragma unroll
      for (int nf = 0; nf < 2; ++nf) {
        acc[mf][nf] = __builtin_amdgcn_mfma_f32_16x16x32_bf16(a03[mf][0], b0[nf][0], acc[mf][nf], 0, 0, 0);
        acc[mf][nf] = __builtin_amdgcn_mfma_f32_16x16x32_bf16(a03[mf][1], b0[nf][1], acc[mf][nf], 0, 0, 0);
      }
    __builtin_amdgcn_s_setprio(0);

    // ========== P2: read b1(u); lgkm(4); BAR; stage A0(u+2); Q10 ==========
    #pragma unroll
    for (int nf = 0; nf < 2; ++nf) {
      const short* q = Bs + (brow + (nf + 2) * 16) * 64;
      b1[nf][0] = *(const short8*)(q + gk0);
      b1[nf][1] = *(const short8*)(q + gk1);
    }
    asm volatile("s_waitcnt lgkmcnt(4)" ::: "memory");  // a47(u) retired
    __builtin_amdgcn_s_barrier();
    if (u + 2 < NT) stage(xb, bm, 0, u + 2, &lds[g][0][0]);
    __builtin_amdgcn_s_setprio(1);
    #pragma unroll
    for (int mf = 0; mf < 4; ++mf)
      #pragma unroll
      for (int nf = 0; nf < 2; ++nf) {
        acc[mf + 4][nf] = __builtin_amdgcn_mfma_f32_16x16x32_bf16(a47[mf][0], b0[nf][0], acc[mf + 4][nf], 0, 0, 0);
        acc[mf + 4][nf] = __builtin_amdgcn_mfma_f32_16x16x32_bf16(a47[mf][1], b0[nf][1], acc[mf + 4][nf], 0, 0, 0);
      }
    __builtin_amdgcn_s_setprio(0);

    // ========== P3: lgkm(0); BAR; stage B0(u+2); Q01 ==========
    asm volatile("s_waitcnt lgkmcnt(0)" ::: "memory");  // b1(u) retired
    __builtin_amdgcn_s_barrier();
    if (u + 2 < NT) stage(wt, bn, 0, u + 2, &lds[g][2][0]);
    __builtin_amdgcn_s_setprio(1);
    #pragma unroll
    for (int mf = 0; mf < 4; ++mf)
      #pragma unroll
      for (int nf = 0; nf < 2; ++nf) {
        acc[mf][nf + 2] = __builtin_amdgcn_mfma_f32_16x16x32_bf16(a03[mf][0], b1[nf][0], acc[mf][nf + 2], 0, 0, 0);
        acc[mf][nf + 2] = __builtin_amdgcn_mfma_f32_16x16x32_bf16(a03[mf][1], b1[nf][1], acc[mf][nf + 2], 0, 0, 0);
      }
    __builtin_amdgcn_s_setprio(0);

    // ========== P4: stage B1(u+2); vmcnt; BAR; read a03,b0(u+1); Q11 ==========
    if (u + 2 < NT) {
      stage(wt, bn, 1, u + 2, &lds[g][3][0]);
      asm volatile("s_waitcnt vmcnt(6)" ::: "memory");  // tile u+1 fully landed
    } else {
      asm volatile("s_waitcnt vmcnt(0)" ::: "memory");
    }
    __builtin_amdgcn_s_barrier();
    if (u + 1 < NT) {
      const short* An = &lds[g ^ 1][wr][0];
      const short* Bn = &lds[g ^ 1][2 + hb][0];
      #pragma unroll
      for (int mf = 0; mf < 4; ++mf) {
        const short* p = An + (mf * 16 + lr) * 64;
        a03[mf][0] = *(const short8*)(p + gk0);
        a03[mf][1] = *(const short8*)(p + gk1);
      }
      #pragma unroll
      for (int nf = 0; nf < 2; ++nf) {
        const short* p = Bn + (brow + nf * 16) * 64;
        b0[nf][0] = *(const short8*)(p + gk0);
        b0[nf][1] = *(const short8*)(p + gk1);
      }
    }
    __builtin_amdgcn_s_setprio(1);
    #pragma unroll
    for (int mf = 0; mf < 4; ++mf)
      #pragma unroll
      for (int nf = 0; nf < 2; ++nf) {
        acc[mf + 4][nf + 2] = __builtin_amdgcn_mfma_f32_16x16x32_bf16(a47[mf][0], b1[nf][0], acc[mf + 4][nf + 2], 0, 0, 0);
        acc[mf + 4][nf + 2] = __builtin_amdgcn_mfma_f32_16x16x32_bf16(a47[mf][1], b1[nf][1], acc[mf + 4][nf + 2], 0, 0, 0);
      }
    __builtin_amdgcn_s_setprio(0);
  }

  // ---- epilogue: out = (G + offset[n]*rowsum[m]) * scale[n] ----
  const int orow0 = bm + wr * 128 + lg * 4;
  const int ocol0 = bn + wc * 64 + lr;
  float4 rsv[8];
  #pragma unroll
  for (int amf = 0; amf < 8; ++amf)
    rsv[amf] = *(const float4*)&rowsum[orow0 + amf * 16];
  #pragma unroll
  for (int anf = 0; anf < 4; ++anf) {
    const int n = ocol0 + anf * 16;
    const float sc = scale[n];
    const float of = offset[n];
    #pragma unroll
    for (int amf = 0; amf < 8; ++amf) {
      const int mbase = orow0 + amf * 16;
      const float4 rv = rsv[amf];
      out[(size_t)(mbase + 0) * N_DIM + n] = (acc[amf][anf][0] + of * rv.x) * sc;
      out[(size_t)(mbase + 1) * N_DIM + n] = (acc[amf][anf][1] + of * rv.y) * sc;
      out[(size_t)(mbase + 2) * N_DIM + n] = (acc[amf][anf][2] + of * rv.z) * sc;
      out[(size_t)(mbase + 3) * N_DIM + n] = (acc[amf][anf][3] + of * rv.w) * sc;
    }
  }
}

// ---------------- fallback (ws too small): exact f32 tiled GEMM ----------------
__global__ __launch_bounds__(256) void fallback_gemm(const float* __restrict__ x,
                                                     const int* __restrict__ w,
                                                     const float* __restrict__ scale,
                                                     const float* __restrict__ offset,
                                                     float* __restrict__ out) {
  __shared__ float xs[32][33];
  __shared__ float bs[32][33];
  const int bm = blockIdx.y * 32, bn = blockIdx.x * 32;
  const int t = threadIdx.x;
  const int tm = t >> 5, tn = t & 31;
  float acc[4] = {0.f, 0.f, 0.f, 0.f};
  for (int k0 = 0; k0 < K_DIM; k0 += 32) {
    #pragma unroll
    for (int i = 0; i < 4; ++i) {
      int idx = t + i * 256; int r = idx >> 5, c = idx & 31;
      xs[r][c] = x[(size_t)(bm + r) * K_DIM + k0 + c];
      bs[r][c] = ((float)w[(size_t)(k0 + r) * N_DIM + bn + c] + offset[bn + c]) * scale[bn + c];
    }
    __syncthreads();
    #pragma unroll 8
    for (int kk = 0; kk < 32; ++kk) {
      float wv = bs[kk][tn];
      #pragma unroll
      for (int i = 0; i < 4; ++i) acc[i] += xs[tm + 8 * i][kk] * wv;
    }
    __syncthreads();
  }
  #pragma unroll
  for (int i = 0; i < 4; ++i)
    out[(size_t)(bm + tm + 8 * i) * N_DIM + bn + tn] = acc[i];
}

extern "C" void kernel_launch(void* const* d_in, const int* in_sizes, int n_in,
                              void* d_out, int out_size, void* d_ws, size_t ws_size,
                              hipStream_t stream) {
  const float* x      = (const float*)d_in[0];
  const int*   w      = (const int*)d_in[1];
  const float* scale  = (const float*)d_in[2];
  const float* offset = (const float*)d_in[3];
  float* out = (float*)d_out;

  const size_t xb_bytes = (size_t)M_DIM * K_DIM * 2;
  const size_t wt_bytes = (size_t)N_DIM * K_DIM * 2;
  const size_t rs_bytes = (size_t)M_DIM * 4;

  if (ws_size >= xb_bytes + wt_bytes + rs_bytes) {
    short* xb = (short*)d_ws;
    short* wt = (short*)((char*)d_ws + xb_bytes);
    float* rowsum = (float*)((char*)d_ws + xb_bytes + wt_bytes);
    convert_x_kernel<<<M_DIM, 256, 0, stream>>>(x, xb, rowsum);
    convert_w_kernel<<<dim3(K_DIM / 64, N_DIM / 64), 256, 0, stream>>>(w, wt);
    gemm_kernel<<<GRID_MN, 512, 0, stream>>>(xb, wt, scale, offset, rowsum, out);
  } else {
    fallback_gemm<<<dim3(N_DIM / 32, M_DIM / 32), 256, 0, stream>>>(x, w, scale, offset, out);
  }
}